// Round 25
// baseline (348.019 us; speedup 1.0000x reference)
//
#include <hip/hip_runtime.h>

// ---- problem geometry ----
#define D_MODEL 512
#define HD      1960
#define NPAD    2048          // HD padded to tile multiple
#define KEFF2   1984          // GEMM2 K loop bound: 31*64 (cols 1960..1983 zero-filled)
#define NVECS   720
#define MROWS   14400         // 4*3600
#define MPAD    14464         // 113*128
#define HP      66
#define WP      114
#define IMGPIX  7524          // HP*WP

typedef __bf16 bf16x8 __attribute__((ext_vector_type(8)));
typedef float  f32x4  __attribute__((ext_vector_type(4)));

__device__ __forceinline__ unsigned short f2bf(float f) {
    unsigned u = __builtin_bit_cast(unsigned, f);
    u += 0x7FFFu + ((u >> 16) & 1u);   // RNE
    return (unsigned short)(u >> 16);
}
__device__ __forceinline__ float bf2f(unsigned short s) {
    unsigned u = ((unsigned)s) << 16;
    return __builtin_bit_cast(float, u);
}

__device__ __forceinline__ void gload_lds16(const unsigned short* g, unsigned short* l) {
    __builtin_amdgcn_global_load_lds(
        (const __attribute__((address_space(1))) unsigned int*)g,
        (__attribute__((address_space(3))) unsigned int*)l,
        16, 0, 0);
}

// ---- fused prep: z=0 cvt x->bf16 (pad rows); z=1 W1->W1T; z=2 W2->W2T ----
__global__ void prep(const float* __restrict__ x,  unsigned short* __restrict__ xb,
                     const float* __restrict__ W1, unsigned short* __restrict__ W1T,
                     const float* __restrict__ W2, unsigned short* __restrict__ W2T) {
    const int z = blockIdx.z;
    const int t = threadIdx.x;
    if (z == 0) {
        size_t i = ((size_t)blockIdx.x * 256 + t) * 4;
        const size_t valid = (size_t)MROWS * D_MODEL;
        if (i >= (size_t)MPAD * D_MODEL) return;
        ushort4 o;
        if (i < valid) {
            float4 v = *(const float4*)(x + i);
            o.x = f2bf(v.x); o.y = f2bf(v.y); o.z = f2bf(v.z); o.w = f2bf(v.w);
        } else {
            o.x = o.y = o.z = o.w = 0;
        }
        *(ushort4*)(xb + i) = o;
        return;
    }
    __shared__ float tile[32][33];
    const int bid = blockIdx.x;
    if (bid >= 1024) return;
    const int tx = t & 31, ty = t >> 5;
    const float* src; unsigned short* dst;
    int srcR, srcC, dstR, dstC, c0, r0;
    if (z == 1) {  // W1 (512x1960) -> W1T (2048x512)
        src = W1; dst = W1T; srcR = 512; srcC = HD; dstR = NPAD; dstC = 512;
        c0 = (bid & 15) * 32; r0 = (bid >> 4) * 32;
    } else {       // W2 (1960x512) -> W2T (512x2048)
        src = W2; dst = W2T; srcR = HD; srcC = 512; dstR = 512; dstC = NPAD;
        c0 = (bid & 63) * 32; r0 = (bid >> 6) * 32;
    }
    #pragma unroll
    for (int i = 0; i < 32; i += 8) {
        int sr = c0 + ty + i, sc = r0 + tx;
        tile[ty + i][tx] = (sr < srcR && sc < srcC) ? src[(size_t)sr * srcC + sc] : 0.f;
    }
    __syncthreads();
    #pragma unroll
    for (int i = 0; i < 32; i += 8) {
        int dr = r0 + ty + i, dc = c0 + tx;
        if (dr < dstR && dc < dstC)
            dst[(size_t)dr * dstC + dc] = f2bf(tile[tx][ty + i]);
    }
}

// ---- 128x128 BK=64 bf16 GEMM, 16 waves, wave-tile 32x32, A DIRECT-FROM-GLOBAL ----
// B in LDS (dbuf 2x16KB, slot-XOR: chunk kq at slot kq^(row&7)), 1 stage-load/thread.
// A fragments loaded per-lane from global (16B contiguous, L2-resident panel).
// Sync: value-driven only — dummy-use of A forces compiler vmcnt(1) (FIFO: own B(t)
// chunk done, B(t+1) in flight) before barrier. No manual vmcnt.
// lda = row stride; K = loop bound (K <= lda; tail cols must be zero).
// MODE 0: out bf16 TRANSPOSED hT[col*MPAD+row], skip cols >= validN (GEMM1)
// MODE 1: out fp32 row-major (ldc=512), skip rows >= validM          (GEMM2)
template<int MODE>
__global__ __launch_bounds__(1024, 8) void gemm_bt(const unsigned short* __restrict__ A,
                        const unsigned short* __restrict__ BT,
                        const float* __restrict__ bias,
                        void* __restrict__ Cout,
                        int K, int lda, int ldc, int validN, int validM) {
    __shared__ unsigned short lds[2][8192];    // 32KB total (B only)
    const int t    = threadIdx.x;
    const int wid  = t >> 6, lane = t & 63;
    const int wr   = wid >> 2, wc = wid & 3;
    const int lr   = lane & 15, lh = lane >> 4;
    const int m0   = blockIdx.y * 128, n0 = blockIdx.x * 128;

    // B staging chunk map: 1024 chunks (128 rows x 8 slots); thread owns chunk t
    const int rr = t >> 3;
    const int qq = (t & 7) ^ (rr & 7);

#define STAGE_B(buf, kt) \
    gload_lds16(BT + (size_t)(n0 + rr) * lda + (kt) + qq * 8, &lds[buf][0] + t * 8)

    // per-lane A fragment base pointers (row = wr*32 + f*16 + lr, k-offset lh*8)
    const unsigned short* Ap0 = A + (size_t)(m0 + wr * 32 +  0 + lr) * lda + lh * 8;
    const unsigned short* Ap1 = A + (size_t)(m0 + wr * 32 + 16 + lr) * lda + lh * 8;

    f32x4 acc[2][2] = {};
    const int NT = K >> 6;

    STAGE_B(0, 0);
    for (int tt = 0; tt < NT; ++tt) {
        // A-frag direct loads for tile tt (issued first -> oldest in VMEM FIFO)
        bf16x8 a0[2], a1[2];
        a0[0] = *(const bf16x8*)(Ap0 + tt * 64);
        a0[1] = *(const bf16x8*)(Ap1 + tt * 64);
        a1[0] = *(const bf16x8*)(Ap0 + tt * 64 + 32);
        a1[1] = *(const bf16x8*)(Ap1 + tt * 64 + 32);
        if (tt + 1 < NT) STAGE_B((tt + 1) & 1, (tt + 1) * 64);
        // force A values ready: compiler emits vmcnt(1) (leaves B(t+1) in flight),
        // which also guarantees this thread's B(t) chunk has landed (FIFO).
        asm volatile("" :: "v"(a0[0]), "v"(a0[1]), "v"(a1[0]), "v"(a1[1]));
        __builtin_amdgcn_s_barrier();
        __builtin_amdgcn_sched_barrier(0);
        const unsigned short* Lb = &lds[tt & 1][0];
        #pragma unroll
        for (int ks = 0; ks < 2; ++ks) {
            const int sl = (ks * 4 + lh) ^ (lr & 7);
            bf16x8 b[2];
            #pragma unroll
            for (int g = 0; g < 2; ++g) {
                int row = wc * 32 + g * 16 + lr;       // row&7 == lr&7
                b[g] = *(const bf16x8*)(Lb + row * 64 + sl * 8);
            }
            bf16x8 aa0 = ks ? a1[0] : a0[0];
            bf16x8 aa1 = ks ? a1[1] : a0[1];
            acc[0][0] = __builtin_amdgcn_mfma_f32_16x16x32_bf16(aa0, b[0], acc[0][0], 0, 0, 0);
            acc[0][1] = __builtin_amdgcn_mfma_f32_16x16x32_bf16(aa0, b[1], acc[0][1], 0, 0, 0);
            acc[1][0] = __builtin_amdgcn_mfma_f32_16x16x32_bf16(aa1, b[0], acc[1][0], 0, 0, 0);
            acc[1][1] = __builtin_amdgcn_mfma_f32_16x16x32_bf16(aa1, b[1], acc[1][1], 0, 0, 0);
        }
        __builtin_amdgcn_s_barrier();
        __builtin_amdgcn_sched_barrier(0);
    }
#undef STAGE_B

    // NOTE on a0/a1 swizzle: A is row-major with natural k-order, matching the
    // verified A-fragment mapping (row=lane&15, k=(lane>>4)*8 + j) per 16x16x32 half.
    // C/D layout: col=lane&15, row=(lane>>4)*4+j  [m89 verified]
    if (MODE == 0) {
        unsigned short* smem = &lds[0][0];   // 16384 ushorts = 32KB (both buffers)
        #pragma unroll
        for (int fm = 0; fm < 2; ++fm) {
            #pragma unroll
            for (int fn = 0; fn < 2; ++fn) {
                int lcol = wc * 32 + fn * 16 + lr;
                float bv = bias[n0 + lcol];
                #pragma unroll
                for (int j = 0; j < 4; ++j) {
                    int lrow = wr * 32 + fm * 16 + lh * 4 + j;
                    smem[lcol * 128 + (lrow ^ ((lcol & 15) << 3))] =
                        f2bf(acc[fm][fn][j] + bv);
                }
            }
        }
        __syncthreads();
        unsigned short* hT = (unsigned short*)Cout;
        int col = t >> 3, q = t & 7;     // 8 threads per column, 4 ushort4 each
        int gcol = n0 + col;
        if (gcol < validN) {
            #pragma unroll
            for (int r = 0; r < 4; ++r) {
                int row = q * 16 + r * 4;
                ushort4 v4 = *(const ushort4*)&smem[col * 128 + (row ^ ((col & 15) << 3))];
                *(ushort4*)&hT[(size_t)gcol * MPAD + m0 + row] = v4;
            }
        }
    } else {
        #pragma unroll
        for (int fm = 0; fm < 2; ++fm) {
            #pragma unroll
            for (int fn = 0; fn < 2; ++fn) {
                int gcol = n0 + wc * 32 + fn * 16 + lr;
                float bv = bias[gcol];
                #pragma unroll
                for (int j = 0; j < 4; ++j) {
                    int grow = m0 + wr * 32 + fm * 16 + lh * 4 + j;
                    if (grow < validM)
                        ((float*)Cout)[(size_t)grow * ldc + gcol] = acc[fm][fn][j] + bv;
                }
            }
        }
    }
}

// ---- fold + normalize + relu -> per-(b2,c) padded image (bf16), 8 ch/thread ----
__global__ void fold_norm(const unsigned short* __restrict__ hT, unsigned short* __restrict__ img2) {
    int y  = blockIdx.x;
    int g  = blockIdx.y;
    int b2 = g / 5, cg = g % 5;
    int c0 = cg * 8;
    int x  = threadIdx.x;
    if (x >= WP) return;
    float val[8] = {};
    if (y >= 3 && y < 63 && x >= 3 && x < 111) {
        int kiA[3], biA[3], nki = 0;
        for (int ki = y % 3; ki < 7; ki += 3) {
            int bi = (y - ki) / 3;
            if (y - ki >= 0 && bi < 20) { kiA[nki] = ki; biA[nki] = bi; ++nki; }
        }
        int kjA[3], bjA[3], nkj = 0;
        for (int kj = x % 3; kj < 7; kj += 3) {
            int bj = (x - kj) / 3;
            if (x - kj >= 0 && bj < 36) { kjA[nkj] = kj; bjA[nkj] = bj; ++nkj; }
        }
        float s[8] = {};
        for (int i = 0; i < nki; ++i) {
            for (int j = 0; j < nkj; ++j) {
                int row = b2 * NVECS + biA[i] * 36 + bjA[j];
                int colb = kiA[i] * 7 + kjA[j];
                #pragma unroll
                for (int q = 0; q < 8; ++q)
                    s[q] += bf2f(hT[(size_t)((c0 + q) * 49 + colb) * MPAD + row]);
            }
        }
        float inv = 1.f / (float)(nki * nkj);
        #pragma unroll
        for (int q = 0; q < 8; ++q)
            val[q] = fmaxf(s[q] * inv, 0.f);
    }
    #pragma unroll
    for (int q = 0; q < 8; ++q)
        img2[(size_t)(b2 * 40 + c0 + q) * IMGPIX + y * WP + x] = f2bf(val[q]);
}

// ---- unfold, LDS-staged ----
__global__ void unfold_k(const unsigned short* __restrict__ img2, unsigned short* __restrict__ h2b) {
    __shared__ unsigned short lds[20 * 798];
    __shared__ unsigned short lut[980];
    const int gb = blockIdx.x;                 // b2*20 + bi
    const int cg = blockIdx.y;
    const int b2 = gb / 20, bi = gb % 20;
    const int t  = threadIdx.x;

    const unsigned short* src = img2 + (size_t)(b2 * 40 + cg * 20) * IMGPIX + (bi * 3) * WP;
    for (int p = t; p < 7980; p += 256) {
        int cc = p / 399, rem2 = p - cc * 399;
        *(ushort2*)&lds[cc * 798 + rem2 * 2] =
            *(const ushort2*)&src[(size_t)cc * IMGPIX + rem2 * 2];
    }
    for (int L = t; L < 980; L += 256) {
        int cc = L / 49, kk = L - cc * 49;
        lut[L] = (unsigned short)(cc * 798 + (kk / 7) * 114 + (kk % 7));
    }
    __syncthreads();

    const int cpr   = (cg == 0) ? 245 : 267;
    const int total = 36 * cpr;
    const int rowbase = b2 * NVECS + bi * 36;
    const int hdbase  = cg * 980;
    for (int i = t; i < total; i += 256) {
        int r = i / cpr, q = i - r * cpr;
        int hl = q * 4;
        ushort4 v;
        unsigned short* vv = (unsigned short*)&v;
        #pragma unroll
        for (int e = 0; e < 4; ++e) {
            int h = hl + e;
            vv[e] = (h < 980) ? lds[lut[h] + r * 3] : (unsigned short)0;
        }
        *(ushort4*)&h2b[(size_t)(rowbase + r) * NPAD + hdbase + hl] = v;
    }
}

extern "C" void kernel_launch(void* const* d_in, const int* in_sizes, int n_in,
                              void* d_out, int out_size, void* d_ws, size_t ws_size,
                              hipStream_t stream) {
    const float* x  = (const float*)d_in[0];
    const float* W1 = (const float*)d_in[1];
    const float* b1 = (const float*)d_in[2];
    const float* W2 = (const float*)d_in[3];
    const float* b2 = (const float*)d_in[4];
    float* out = (float*)d_out;

    unsigned short* xb   = (unsigned short*)d_ws;                 // MPAD*512
    unsigned short* W1T  = xb   + (size_t)MPAD * D_MODEL;         // 2048*512
    unsigned short* W2T  = W1T  + (size_t)NPAD * D_MODEL;         // 512*2048
    unsigned short* hT   = W2T  + (size_t)D_MODEL * NPAD;         // NPAD*MPAD (transposed)
    unsigned short* h2b  = hT   + (size_t)NPAD * MPAD;            // MPAD*NPAD
    unsigned short* img2 = h2b  + (size_t)MPAD * NPAD;            // 800*7524

    prep<<<dim3((MPAD * D_MODEL / 4 + 255) / 256, 1, 3), 256, 0, stream>>>(
        x, xb, W1, W1T, W2, W2T);

    // GEMM1: hT = (xb @ W1T^T + b1)^T   (bf16, transposed out), grid 16x113, 1024 thr
    gemm_bt<0><<<dim3(NPAD / 128, MPAD / 128), 1024, 0, stream>>>(
        xb, W1T, b1, hT, D_MODEL, D_MODEL, 0, HD, MPAD);

    fold_norm<<<dim3(HP, 100), 128, 0, stream>>>(hT, img2);
    unfold_k<<<dim3(400, 2), 256, 0, stream>>>(img2, h2b);

    // GEMM2: out = h2b @ W2T^T + b2  (fp32, rows<14400), grid 4x113, 1024 thr, K=1984
    gemm_bt<1><<<dim3(512 / 128, MPAD / 128), 1024, 0, stream>>>(
        h2b, W2T, b2, out, KEFF2, NPAD, D_MODEL, D_MODEL, MROWS);
}

// Round 26
// 161.889 us; speedup vs baseline: 2.1497x; 2.1497x over previous
//
#include <hip/hip_runtime.h>

// ---- problem geometry ----
#define D_MODEL 512
#define HD      1960
#define NPAD    2048          // HD padded to tile multiple
#define KEFF2   1984          // GEMM2 K loop bound: 31*64 (cols 1960..1983 zero-filled)
#define NVECS   720
#define MROWS   14400         // 4*3600
#define MPAD    14464         // 113*128
#define HP      66
#define WP      114
#define IMGPIX  7524          // HP*WP

typedef __bf16 bf16x8 __attribute__((ext_vector_type(8)));
typedef float  f32x4  __attribute__((ext_vector_type(4)));

__device__ __forceinline__ unsigned short f2bf(float f) {
    unsigned u = __builtin_bit_cast(unsigned, f);
    u += 0x7FFFu + ((u >> 16) & 1u);   // RNE
    return (unsigned short)(u >> 16);
}
__device__ __forceinline__ float bf2f(unsigned short s) {
    unsigned u = ((unsigned)s) << 16;
    return __builtin_bit_cast(float, u);
}

__device__ __forceinline__ void gload_lds16(const unsigned short* g, unsigned short* l) {
    __builtin_amdgcn_global_load_lds(
        (const __attribute__((address_space(1))) unsigned int*)g,
        (__attribute__((address_space(3))) unsigned int*)l,
        16, 0, 0);
}

// ---- fused prep: z=0 cvt x->bf16 (pad rows); z=1 W1->W1T; z=2 W2->W2T ----
__global__ void prep(const float* __restrict__ x,  unsigned short* __restrict__ xb,
                     const float* __restrict__ W1, unsigned short* __restrict__ W1T,
                     const float* __restrict__ W2, unsigned short* __restrict__ W2T) {
    const int z = blockIdx.z;
    const int t = threadIdx.x;
    if (z == 0) {
        size_t i = ((size_t)blockIdx.x * 256 + t) * 4;
        const size_t valid = (size_t)MROWS * D_MODEL;
        if (i >= (size_t)MPAD * D_MODEL) return;
        ushort4 o;
        if (i < valid) {
            float4 v = *(const float4*)(x + i);
            o.x = f2bf(v.x); o.y = f2bf(v.y); o.z = f2bf(v.z); o.w = f2bf(v.w);
        } else {
            o.x = o.y = o.z = o.w = 0;
        }
        *(ushort4*)(xb + i) = o;
        return;
    }
    __shared__ float tile[32][33];
    const int bid = blockIdx.x;
    if (bid >= 1024) return;
    const int tx = t & 31, ty = t >> 5;
    const float* src; unsigned short* dst;
    int srcR, srcC, dstR, dstC, c0, r0;
    if (z == 1) {  // W1 (512x1960) -> W1T (2048x512)
        src = W1; dst = W1T; srcR = 512; srcC = HD; dstR = NPAD; dstC = 512;
        c0 = (bid & 15) * 32; r0 = (bid >> 4) * 32;
    } else {       // W2 (1960x512) -> W2T (512x2048)
        src = W2; dst = W2T; srcR = HD; srcC = 512; dstR = 512; dstC = NPAD;
        c0 = (bid & 63) * 32; r0 = (bid >> 6) * 32;
    }
    #pragma unroll
    for (int i = 0; i < 32; i += 8) {
        int sr = c0 + ty + i, sc = r0 + tx;
        tile[ty + i][tx] = (sr < srcR && sc < srcC) ? src[(size_t)sr * srcC + sc] : 0.f;
    }
    __syncthreads();
    #pragma unroll
    for (int i = 0; i < 32; i += 8) {
        int dr = r0 + ty + i, dc = c0 + tx;
        if (dr < dstR && dc < dstC)
            dst[(size_t)dr * dstC + dc] = f2bf(tile[tx][ty + i]);
    }
}

// ---- 128x128 BK=64 dbuf counted-vmcnt bf16 GEMM, 16 waves, wave-tile 32x32 ----
// (R24 config: best measured. No setprio — m190 lockstep-null confirmed here.)
// Wave grid: wr = wid>>2 (0..3, m), wc = wid&3 (0..3, n); acc 2x2.
// LDS 64KB = 2 bufs x [A 16KB | B 16KB], slot-XOR (chunk kq at slot kq^(row&7)).
// Staging: 2 loads/thread/tile -> steady vmcnt(2), never 0 in-loop.
// lda = row stride; K = loop bound (K <= lda; tail cols must be zero).
// MODE 0: out bf16 TRANSPOSED hT[col*MPAD+row], skip cols >= validN (GEMM1)
// MODE 1: out fp32 row-major (ldc=512), skip rows >= validM          (GEMM2)
template<int MODE>
__global__ __launch_bounds__(1024, 8) void gemm_bt(const unsigned short* __restrict__ A,
                        const unsigned short* __restrict__ BT,
                        const float* __restrict__ bias,
                        void* __restrict__ Cout,
                        int K, int lda, int ldc, int validN, int validM) {
    __shared__ unsigned short lds[2][16384];   // 64KB total
    const int t    = threadIdx.x;
    const int wid  = t >> 6, lane = t & 63;
    const int wr   = wid >> 2, wc = wid & 3;
    const int lr   = lane & 15, lh = lane >> 4;
    const int m0   = blockIdx.y * 128, n0 = blockIdx.x * 128;

    // staging chunk map: 1024 chunks per matrix tile; thread owns chunk t of each
    const int rr = t >> 3;
    const int qq = (t & 7) ^ (rr & 7);

#define STAGE(buf, kt) do { \
        gload_lds16(A  + (size_t)(m0 + rr) * lda + (kt) + qq * 8, &lds[buf][0]    + t * 8); \
        gload_lds16(BT + (size_t)(n0 + rr) * lda + (kt) + qq * 8, &lds[buf][8192] + t * 8); \
    } while (0)

    f32x4 acc[2][2] = {};
    const int NT = K >> 6;

    STAGE(0, 0);
    for (int tt = 0; tt < NT; ++tt) {
        if (tt + 1 < NT) {
            STAGE((tt + 1) & 1, (tt + 1) * 64);
            asm volatile("s_waitcnt vmcnt(2)" ::: "memory");
        } else {
            asm volatile("s_waitcnt vmcnt(0)" ::: "memory");
        }
        __builtin_amdgcn_s_barrier();
        __builtin_amdgcn_sched_barrier(0);
        const unsigned short* La = &lds[tt & 1][0];
        const unsigned short* Lb = &lds[tt & 1][8192];
        #pragma unroll
        for (int ks = 0; ks < 2; ++ks) {
            const int sl = (ks * 4 + lh) ^ (lr & 7);
            bf16x8 a[2], b[2];
            #pragma unroll
            for (int f = 0; f < 2; ++f) {
                int row = wr * 32 + f * 16 + lr;       // row&7 == lr&7
                a[f] = *(const bf16x8*)(La + row * 64 + sl * 8);
            }
            #pragma unroll
            for (int g = 0; g < 2; ++g) {
                int row = wc * 32 + g * 16 + lr;
                b[g] = *(const bf16x8*)(Lb + row * 64 + sl * 8);
            }
            #pragma unroll
            for (int fm = 0; fm < 2; ++fm)
                #pragma unroll
                for (int fn = 0; fn < 2; ++fn)
                    acc[fm][fn] = __builtin_amdgcn_mfma_f32_16x16x32_bf16(
                        a[fm], b[fn], acc[fm][fn], 0, 0, 0);
        }
        __builtin_amdgcn_s_barrier();
        __builtin_amdgcn_sched_barrier(0);
    }
#undef STAGE

    // C/D layout: col=lane&15, row=(lane>>4)*4+j  [m89 verified]
    if (MODE == 0) {
        unsigned short* smem = &lds[0][0];   // 16384 ushorts = 32KB
        #pragma unroll
        for (int fm = 0; fm < 2; ++fm) {
            #pragma unroll
            for (int fn = 0; fn < 2; ++fn) {
                int lcol = wc * 32 + fn * 16 + lr;
                float bv = bias[n0 + lcol];
                #pragma unroll
                for (int j = 0; j < 4; ++j) {
                    int lrow = wr * 32 + fm * 16 + lh * 4 + j;
                    smem[lcol * 128 + (lrow ^ ((lcol & 15) << 3))] =
                        f2bf(acc[fm][fn][j] + bv);
                }
            }
        }
        __syncthreads();
        unsigned short* hT = (unsigned short*)Cout;
        int col = t >> 3, q = t & 7;     // 8 threads per column, 4 ushort4 each
        int gcol = n0 + col;
        if (gcol < validN) {
            #pragma unroll
            for (int r = 0; r < 4; ++r) {
                int row = q * 16 + r * 4;
                ushort4 v4 = *(const ushort4*)&smem[col * 128 + (row ^ ((col & 15) << 3))];
                *(ushort4*)&hT[(size_t)gcol * MPAD + m0 + row] = v4;
            }
        }
    } else {
        #pragma unroll
        for (int fm = 0; fm < 2; ++fm) {
            #pragma unroll
            for (int fn = 0; fn < 2; ++fn) {
                int gcol = n0 + wc * 32 + fn * 16 + lr;
                float bv = bias[gcol];
                #pragma unroll
                for (int j = 0; j < 4; ++j) {
                    int grow = m0 + wr * 32 + fm * 16 + lh * 4 + j;
                    if (grow < validM)
                        ((float*)Cout)[(size_t)grow * ldc + gcol] = acc[fm][fn][j] + bv;
                }
            }
        }
    }
}

// ---- fold + normalize + relu -> per-(b2,c) padded image (bf16), 8 ch/thread ----
__global__ void fold_norm(const unsigned short* __restrict__ hT, unsigned short* __restrict__ img2) {
    int y  = blockIdx.x;
    int g  = blockIdx.y;
    int b2 = g / 5, cg = g % 5;
    int c0 = cg * 8;
    int x  = threadIdx.x;
    if (x >= WP) return;
    float val[8] = {};
    if (y >= 3 && y < 63 && x >= 3 && x < 111) {
        int kiA[3], biA[3], nki = 0;
        for (int ki = y % 3; ki < 7; ki += 3) {
            int bi = (y - ki) / 3;
            if (y - ki >= 0 && bi < 20) { kiA[nki] = ki; biA[nki] = bi; ++nki; }
        }
        int kjA[3], bjA[3], nkj = 0;
        for (int kj = x % 3; kj < 7; kj += 3) {
            int bj = (x - kj) / 3;
            if (x - kj >= 0 && bj < 36) { kjA[nkj] = kj; bjA[nkj] = bj; ++nkj; }
        }
        float s[8] = {};
        for (int i = 0; i < nki; ++i) {
            for (int j = 0; j < nkj; ++j) {
                int row = b2 * NVECS + biA[i] * 36 + bjA[j];
                int colb = kiA[i] * 7 + kjA[j];
                #pragma unroll
                for (int q = 0; q < 8; ++q)
                    s[q] += bf2f(hT[(size_t)((c0 + q) * 49 + colb) * MPAD + row]);
            }
        }
        float inv = 1.f / (float)(nki * nkj);
        #pragma unroll
        for (int q = 0; q < 8; ++q)
            val[q] = fmaxf(s[q] * inv, 0.f);
    }
    #pragma unroll
    for (int q = 0; q < 8; ++q)
        img2[(size_t)(b2 * 40 + c0 + q) * IMGPIX + y * WP + x] = f2bf(val[q]);
}

// ---- unfold, LDS-staged ----
__global__ void unfold_k(const unsigned short* __restrict__ img2, unsigned short* __restrict__ h2b) {
    __shared__ unsigned short lds[20 * 798];
    __shared__ unsigned short lut[980];
    const int gb = blockIdx.x;                 // b2*20 + bi
    const int cg = blockIdx.y;
    const int b2 = gb / 20, bi = gb % 20;
    const int t  = threadIdx.x;

    const unsigned short* src = img2 + (size_t)(b2 * 40 + cg * 20) * IMGPIX + (bi * 3) * WP;
    for (int p = t; p < 7980; p += 256) {
        int cc = p / 399, rem2 = p - cc * 399;
        *(ushort2*)&lds[cc * 798 + rem2 * 2] =
            *(const ushort2*)&src[(size_t)cc * IMGPIX + rem2 * 2];
    }
    for (int L = t; L < 980; L += 256) {
        int cc = L / 49, kk = L - cc * 49;
        lut[L] = (unsigned short)(cc * 798 + (kk / 7) * 114 + (kk % 7));
    }
    __syncthreads();

    const int cpr   = (cg == 0) ? 245 : 267;
    const int total = 36 * cpr;
    const int rowbase = b2 * NVECS + bi * 36;
    const int hdbase  = cg * 980;
    for (int i = t; i < total; i += 256) {
        int r = i / cpr, q = i - r * cpr;
        int hl = q * 4;
        ushort4 v;
        unsigned short* vv = (unsigned short*)&v;
        #pragma unroll
        for (int e = 0; e < 4; ++e) {
            int h = hl + e;
            vv[e] = (h < 980) ? lds[lut[h] + r * 3] : (unsigned short)0;
        }
        *(ushort4*)&h2b[(size_t)(rowbase + r) * NPAD + hdbase + hl] = v;
    }
}

extern "C" void kernel_launch(void* const* d_in, const int* in_sizes, int n_in,
                              void* d_out, int out_size, void* d_ws, size_t ws_size,
                              hipStream_t stream) {
    const float* x  = (const float*)d_in[0];
    const float* W1 = (const float*)d_in[1];
    const float* b1 = (const float*)d_in[2];
    const float* W2 = (const float*)d_in[3];
    const float* b2 = (const float*)d_in[4];
    float* out = (float*)d_out;

    unsigned short* xb   = (unsigned short*)d_ws;                 // MPAD*512
    unsigned short* W1T  = xb   + (size_t)MPAD * D_MODEL;         // 2048*512
    unsigned short* W2T  = W1T  + (size_t)NPAD * D_MODEL;         // 512*2048
    unsigned short* hT   = W2T  + (size_t)D_MODEL * NPAD;         // NPAD*MPAD (transposed)
    unsigned short* h2b  = hT   + (size_t)NPAD * MPAD;            // MPAD*NPAD
    unsigned short* img2 = h2b  + (size_t)MPAD * NPAD;            // 800*7524

    prep<<<dim3((MPAD * D_MODEL / 4 + 255) / 256, 1, 3), 256, 0, stream>>>(
        x, xb, W1, W1T, W2, W2T);

    // GEMM1: hT = (xb @ W1T^T + b1)^T   (bf16, transposed out), grid 16x113, 1024 thr
    gemm_bt<0><<<dim3(NPAD / 128, MPAD / 128), 1024, 0, stream>>>(
        xb, W1T, b1, hT, D_MODEL, D_MODEL, 0, HD, MPAD);

    fold_norm<<<dim3(HP, 100), 128, 0, stream>>>(hT, img2);
    unfold_k<<<dim3(400, 2), 256, 0, stream>>>(img2, h2b);

    // GEMM2: out = h2b @ W2T^T + b2  (fp32, rows<14400), grid 4x113, 1024 thr, K=1984
    gemm_bt<1><<<dim3(512 / 128, MPAD / 128), 1024, 0, stream>>>(
        h2b, W2T, b2, out, KEFF2, NPAD, D_MODEL, D_MODEL, MROWS);
}

// Round 27
// 156.105 us; speedup vs baseline: 2.2294x; 1.0370x over previous
//
#include <hip/hip_runtime.h>

// ---- problem geometry ----
#define D_MODEL 512
#define HD      1960
#define NPAD    2048          // HD padded to tile multiple
#define KEFF2   1984          // GEMM2 K loop bound: 31*64 (cols 1960..1983 zero-filled)
#define NVECS   720
#define MROWS   14400         // 4*3600
#define MPAD    14464         // 113*128
#define HP      66
#define WP      114
#define IMGPIX  7524          // HP*WP

typedef __bf16 bf16x8 __attribute__((ext_vector_type(8)));
typedef float  f32x4  __attribute__((ext_vector_type(4)));

__device__ __forceinline__ unsigned short f2bf(float f) {
    unsigned u = __builtin_bit_cast(unsigned, f);
    u += 0x7FFFu + ((u >> 16) & 1u);   // RNE
    return (unsigned short)(u >> 16);
}
__device__ __forceinline__ float bf2f(unsigned short s) {
    unsigned u = ((unsigned)s) << 16;
    return __builtin_bit_cast(float, u);
}

__device__ __forceinline__ void gload_lds16(const unsigned short* g, unsigned short* l) {
    __builtin_amdgcn_global_load_lds(
        (const __attribute__((address_space(1))) unsigned int*)g,
        (__attribute__((address_space(3))) unsigned int*)l,
        16, 0, 0);
}

// ---- fused prep: z=0 cvt x->bf16 (pad rows); z=1 W1->W1T; z=2 W2->W2T ----
__global__ void prep(const float* __restrict__ x,  unsigned short* __restrict__ xb,
                     const float* __restrict__ W1, unsigned short* __restrict__ W1T,
                     const float* __restrict__ W2, unsigned short* __restrict__ W2T) {
    const int z = blockIdx.z;
    const int t = threadIdx.x;
    if (z == 0) {
        size_t i = ((size_t)blockIdx.x * 256 + t) * 4;
        const size_t valid = (size_t)MROWS * D_MODEL;
        if (i >= (size_t)MPAD * D_MODEL) return;
        ushort4 o;
        if (i < valid) {
            float4 v = *(const float4*)(x + i);
            o.x = f2bf(v.x); o.y = f2bf(v.y); o.z = f2bf(v.z); o.w = f2bf(v.w);
        } else {
            o.x = o.y = o.z = o.w = 0;
        }
        *(ushort4*)(xb + i) = o;
        return;
    }
    __shared__ float tile[32][33];
    const int bid = blockIdx.x;
    if (bid >= 1024) return;
    const int tx = t & 31, ty = t >> 5;
    const float* src; unsigned short* dst;
    int srcR, srcC, dstR, dstC, c0, r0;
    if (z == 1) {  // W1 (512x1960) -> W1T (2048x512)
        src = W1; dst = W1T; srcR = 512; srcC = HD; dstR = NPAD; dstC = 512;
        c0 = (bid & 15) * 32; r0 = (bid >> 4) * 32;
    } else {       // W2 (1960x512) -> W2T (512x2048)
        src = W2; dst = W2T; srcR = HD; srcC = 512; dstR = 512; dstC = NPAD;
        c0 = (bid & 63) * 32; r0 = (bid >> 6) * 32;
    }
    #pragma unroll
    for (int i = 0; i < 32; i += 8) {
        int sr = c0 + ty + i, sc = r0 + tx;
        tile[ty + i][tx] = (sr < srcR && sc < srcC) ? src[(size_t)sr * srcC + sc] : 0.f;
    }
    __syncthreads();
    #pragma unroll
    for (int i = 0; i < 32; i += 8) {
        int dr = r0 + ty + i, dc = c0 + tx;
        if (dr < dstR && dc < dstC)
            dst[(size_t)dr * dstC + dc] = f2bf(tile[tx][ty + i]);
    }
}

// ---- 128x128 BK=64 dbuf counted-vmcnt bf16 GEMM, 16 waves, wave-tile 32x32 ----
// R27: + bijective XCD-chunked swizzle (m204) — same-A-panel n-blocks land on one XCD's L2.
// Wave grid: wr = wid>>2 (0..3, m), wc = wid&3 (0..3, n); acc 2x2.
// LDS 64KB = 2 bufs x [A 16KB | B 16KB], slot-XOR (chunk kq at slot kq^(row&7)).
// Staging: 2 loads/thread/tile -> steady vmcnt(2), never 0 in-loop.
// lda = row stride; K = loop bound (K <= lda; tail cols must be zero).
// MODE 0: out bf16 TRANSPOSED hT[col*MPAD+row], skip cols >= validN (GEMM1)
// MODE 1: out fp32 row-major (ldc=512), skip rows >= validM          (GEMM2)
template<int MODE>
__global__ __launch_bounds__(1024, 8) void gemm_bt(const unsigned short* __restrict__ A,
                        const unsigned short* __restrict__ BT,
                        const float* __restrict__ bias,
                        void* __restrict__ Cout,
                        int K, int lda, int ldc, int validN, int validM) {
    __shared__ unsigned short lds[2][16384];   // 64KB total
    const int t    = threadIdx.x;
    const int wid  = t >> 6, lane = t & 63;
    const int wr   = wid >> 2, wc = wid & 3;
    const int lr   = lane & 15, lh = lane >> 4;

    // bijective XCD-chunked swizzle (m204): XCD k = bid%8 owns a contiguous wgid chunk;
    // consecutive wgids walk n-fast -> same-A-panel blocks share an XCD L2.
    const int nwg = gridDim.x * gridDim.y;
    const int bid = blockIdx.x + blockIdx.y * gridDim.x;
    const int xcd = bid & 7, idx = bid >> 3;
    const int qc  = nwg >> 3, rc = nwg & 7;
    const int swz = (xcd < rc ? xcd * (qc + 1) : rc * (qc + 1) + (xcd - rc) * qc) + idx;
    const int m0  = (swz / gridDim.x) * 128, n0 = (swz % gridDim.x) * 128;

    // staging chunk map: 1024 chunks per matrix tile; thread owns chunk t of each
    const int rr = t >> 3;
    const int qq = (t & 7) ^ (rr & 7);

#define STAGE(buf, kt) do { \
        gload_lds16(A  + (size_t)(m0 + rr) * lda + (kt) + qq * 8, &lds[buf][0]    + t * 8); \
        gload_lds16(BT + (size_t)(n0 + rr) * lda + (kt) + qq * 8, &lds[buf][8192] + t * 8); \
    } while (0)

    f32x4 acc[2][2] = {};
    const int NT = K >> 6;

    STAGE(0, 0);
    for (int tt = 0; tt < NT; ++tt) {
        if (tt + 1 < NT) {
            STAGE((tt + 1) & 1, (tt + 1) * 64);
            asm volatile("s_waitcnt vmcnt(2)" ::: "memory");
        } else {
            asm volatile("s_waitcnt vmcnt(0)" ::: "memory");
        }
        __builtin_amdgcn_s_barrier();
        __builtin_amdgcn_sched_barrier(0);
        const unsigned short* La = &lds[tt & 1][0];
        const unsigned short* Lb = &lds[tt & 1][8192];
        #pragma unroll
        for (int ks = 0; ks < 2; ++ks) {
            const int sl = (ks * 4 + lh) ^ (lr & 7);
            bf16x8 a[2], b[2];
            #pragma unroll
            for (int f = 0; f < 2; ++f) {
                int row = wr * 32 + f * 16 + lr;       // row&7 == lr&7
                a[f] = *(const bf16x8*)(La + row * 64 + sl * 8);
            }
            #pragma unroll
            for (int g = 0; g < 2; ++g) {
                int row = wc * 32 + g * 16 + lr;
                b[g] = *(const bf16x8*)(Lb + row * 64 + sl * 8);
            }
            #pragma unroll
            for (int fm = 0; fm < 2; ++fm)
                #pragma unroll
                for (int fn = 0; fn < 2; ++fn)
                    acc[fm][fn] = __builtin_amdgcn_mfma_f32_16x16x32_bf16(
                        a[fm], b[fn], acc[fm][fn], 0, 0, 0);
        }
        __builtin_amdgcn_s_barrier();
        __builtin_amdgcn_sched_barrier(0);
    }
#undef STAGE

    // C/D layout: col=lane&15, row=(lane>>4)*4+j  [m89 verified]
    if (MODE == 0) {
        unsigned short* smem = &lds[0][0];   // 16384 ushorts = 32KB
        #pragma unroll
        for (int fm = 0; fm < 2; ++fm) {
            #pragma unroll
            for (int fn = 0; fn < 2; ++fn) {
                int lcol = wc * 32 + fn * 16 + lr;
                float bv = bias[n0 + lcol];
                #pragma unroll
                for (int j = 0; j < 4; ++j) {
                    int lrow = wr * 32 + fm * 16 + lh * 4 + j;
                    smem[lcol * 128 + (lrow ^ ((lcol & 15) << 3))] =
                        f2bf(acc[fm][fn][j] + bv);
                }
            }
        }
        __syncthreads();
        unsigned short* hT = (unsigned short*)Cout;
        int col = t >> 3, q = t & 7;     // 8 threads per column, 4 ushort4 each
        int gcol = n0 + col;
        if (gcol < validN) {
            #pragma unroll
            for (int r = 0; r < 4; ++r) {
                int row = q * 16 + r * 4;
                ushort4 v4 = *(const ushort4*)&smem[col * 128 + (row ^ ((col & 15) << 3))];
                *(ushort4*)&hT[(size_t)gcol * MPAD + m0 + row] = v4;
            }
        }
    } else {
        #pragma unroll
        for (int fm = 0; fm < 2; ++fm) {
            #pragma unroll
            for (int fn = 0; fn < 2; ++fn) {
                int gcol = n0 + wc * 32 + fn * 16 + lr;
                float bv = bias[gcol];
                #pragma unroll
                for (int j = 0; j < 4; ++j) {
                    int grow = m0 + wr * 32 + fm * 16 + lh * 4 + j;
                    if (grow < validM)
                        ((float*)Cout)[(size_t)grow * ldc + gcol] = acc[fm][fn][j] + bv;
                }
            }
        }
    }
}

// ---- fold + normalize + relu -> per-(b2,c) padded image (bf16), 8 ch/thread ----
__global__ void fold_norm(const unsigned short* __restrict__ hT, unsigned short* __restrict__ img2) {
    int y  = blockIdx.x;
    int g  = blockIdx.y;
    int b2 = g / 5, cg = g % 5;
    int c0 = cg * 8;
    int x  = threadIdx.x;
    if (x >= WP) return;
    float val[8] = {};
    if (y >= 3 && y < 63 && x >= 3 && x < 111) {
        int kiA[3], biA[3], nki = 0;
        for (int ki = y % 3; ki < 7; ki += 3) {
            int bi = (y - ki) / 3;
            if (y - ki >= 0 && bi < 20) { kiA[nki] = ki; biA[nki] = bi; ++nki; }
        }
        int kjA[3], bjA[3], nkj = 0;
        for (int kj = x % 3; kj < 7; kj += 3) {
            int bj = (x - kj) / 3;
            if (x - kj >= 0 && bj < 36) { kjA[nkj] = kj; bjA[nkj] = bj; ++nkj; }
        }
        float s[8] = {};
        for (int i = 0; i < nki; ++i) {
            for (int j = 0; j < nkj; ++j) {
                int row = b2 * NVECS + biA[i] * 36 + bjA[j];
                int colb = kiA[i] * 7 + kjA[j];
                #pragma unroll
                for (int q = 0; q < 8; ++q)
                    s[q] += bf2f(hT[(size_t)((c0 + q) * 49 + colb) * MPAD + row]);
            }
        }
        float inv = 1.f / (float)(nki * nkj);
        #pragma unroll
        for (int q = 0; q < 8; ++q)
            val[q] = fmaxf(s[q] * inv, 0.f);
    }
    #pragma unroll
    for (int q = 0; q < 8; ++q)
        img2[(size_t)(b2 * 40 + c0 + q) * IMGPIX + y * WP + x] = f2bf(val[q]);
}

// ---- unfold, LDS-staged ----
__global__ void unfold_k(const unsigned short* __restrict__ img2, unsigned short* __restrict__ h2b) {
    __shared__ unsigned short lds[20 * 798];
    __shared__ unsigned short lut[980];
    const int gb = blockIdx.x;                 // b2*20 + bi
    const int cg = blockIdx.y;
    const int b2 = gb / 20, bi = gb % 20;
    const int t  = threadIdx.x;

    const unsigned short* src = img2 + (size_t)(b2 * 40 + cg * 20) * IMGPIX + (bi * 3) * WP;
    for (int p = t; p < 7980; p += 256) {
        int cc = p / 399, rem2 = p - cc * 399;
        *(ushort2*)&lds[cc * 798 + rem2 * 2] =
            *(const ushort2*)&src[(size_t)cc * IMGPIX + rem2 * 2];
    }
    for (int L = t; L < 980; L += 256) {
        int cc = L / 49, kk = L - cc * 49;
        lut[L] = (unsigned short)(cc * 798 + (kk / 7) * 114 + (kk % 7));
    }
    __syncthreads();

    const int cpr   = (cg == 0) ? 245 : 267;
    const int total = 36 * cpr;
    const int rowbase = b2 * NVECS + bi * 36;
    const int hdbase  = cg * 980;
    for (int i = t; i < total; i += 256) {
        int r = i / cpr, q = i - r * cpr;
        int hl = q * 4;
        ushort4 v;
        unsigned short* vv = (unsigned short*)&v;
        #pragma unroll
        for (int e = 0; e < 4; ++e) {
            int h = hl + e;
            vv[e] = (h < 980) ? lds[lut[h] + r * 3] : (unsigned short)0;
        }
        *(ushort4*)&h2b[(size_t)(rowbase + r) * NPAD + hdbase + hl] = v;
    }
}

extern "C" void kernel_launch(void* const* d_in, const int* in_sizes, int n_in,
                              void* d_out, int out_size, void* d_ws, size_t ws_size,
                              hipStream_t stream) {
    const float* x  = (const float*)d_in[0];
    const float* W1 = (const float*)d_in[1];
    const float* b1 = (const float*)d_in[2];
    const float* W2 = (const float*)d_in[3];
    const float* b2 = (const float*)d_in[4];
    float* out = (float*)d_out;

    unsigned short* xb   = (unsigned short*)d_ws;                 // MPAD*512
    unsigned short* W1T  = xb   + (size_t)MPAD * D_MODEL;         // 2048*512
    unsigned short* W2T  = W1T  + (size_t)NPAD * D_MODEL;         // 512*2048
    unsigned short* hT   = W2T  + (size_t)D_MODEL * NPAD;         // NPAD*MPAD (transposed)
    unsigned short* h2b  = hT   + (size_t)NPAD * MPAD;            // MPAD*NPAD
    unsigned short* img2 = h2b  + (size_t)MPAD * NPAD;            // 800*7524

    prep<<<dim3((MPAD * D_MODEL / 4 + 255) / 256, 1, 3), 256, 0, stream>>>(
        x, xb, W1, W1T, W2, W2T);

    // GEMM1: hT = (xb @ W1T^T + b1)^T   (bf16, transposed out), grid 16x113, 1024 thr
    gemm_bt<0><<<dim3(NPAD / 128, MPAD / 128), 1024, 0, stream>>>(
        xb, W1T, b1, hT, D_MODEL, D_MODEL, 0, HD, MPAD);

    fold_norm<<<dim3(HP, 100), 128, 0, stream>>>(hT, img2);
    unfold_k<<<dim3(400, 2), 256, 0, stream>>>(img2, h2b);

    // GEMM2: out = h2b @ W2T^T + b2  (fp32, rows<14400), grid 4x113, 1024 thr, K=1984
    gemm_bt<1><<<dim3(512 / 128, MPAD / 128), 1024, 0, stream>>>(
        h2b, W2T, b2, out, KEFF2, NPAD, D_MODEL, D_MODEL, MROWS);
}

// Round 28
// 153.640 us; speedup vs baseline: 2.2652x; 1.0160x over previous
//
#include <hip/hip_runtime.h>

// ---- problem geometry ----
#define D_MODEL 512
#define HD      1960
#define NPAD    2048          // HD padded to tile multiple
#define KEFF2   1984          // GEMM2 K loop bound: 31*64 (cols 1960..1983 zero-filled)
#define NVECS   720
#define MROWS   14400         // 4*3600
#define MPAD    14464         // 113*128
#define HP      66
#define WP      114
#define IMGPIX  7524          // HP*WP

typedef __bf16 bf16x8 __attribute__((ext_vector_type(8)));
typedef float  f32x4  __attribute__((ext_vector_type(4)));

__device__ __forceinline__ unsigned short f2bf(float f) {
    unsigned u = __builtin_bit_cast(unsigned, f);
    u += 0x7FFFu + ((u >> 16) & 1u);   // RNE
    return (unsigned short)(u >> 16);
}
__device__ __forceinline__ float bf2f(unsigned short s) {
    unsigned u = ((unsigned)s) << 16;
    return __builtin_bit_cast(float, u);
}

__device__ __forceinline__ void gload_lds16(const unsigned short* g, unsigned short* l) {
    __builtin_amdgcn_global_load_lds(
        (const __attribute__((address_space(1))) unsigned int*)g,
        (__attribute__((address_space(3))) unsigned int*)l,
        16, 0, 0);
}

// ---- fused prep: z=0 cvt x->bf16 (pad rows); z=1 W1->W1T; z=2 W2->W2T ----
__global__ void prep(const float* __restrict__ x,  unsigned short* __restrict__ xb,
                     const float* __restrict__ W1, unsigned short* __restrict__ W1T,
                     const float* __restrict__ W2, unsigned short* __restrict__ W2T) {
    const int z = blockIdx.z;
    const int t = threadIdx.x;
    if (z == 0) {
        size_t i = ((size_t)blockIdx.x * 256 + t) * 4;
        const size_t valid = (size_t)MROWS * D_MODEL;
        if (i >= (size_t)MPAD * D_MODEL) return;
        ushort4 o;
        if (i < valid) {
            float4 v = *(const float4*)(x + i);
            o.x = f2bf(v.x); o.y = f2bf(v.y); o.z = f2bf(v.z); o.w = f2bf(v.w);
        } else {
            o.x = o.y = o.z = o.w = 0;
        }
        *(ushort4*)(xb + i) = o;
        return;
    }
    __shared__ float tile[32][33];
    const int bid = blockIdx.x;
    if (bid >= 1024) return;
    const int tx = t & 31, ty = t >> 5;
    const float* src; unsigned short* dst;
    int srcR, srcC, dstR, dstC, c0, r0;
    if (z == 1) {  // W1 (512x1960) -> W1T (2048x512)
        src = W1; dst = W1T; srcR = 512; srcC = HD; dstR = NPAD; dstC = 512;
        c0 = (bid & 15) * 32; r0 = (bid >> 4) * 32;
    } else {       // W2 (1960x512) -> W2T (512x2048)
        src = W2; dst = W2T; srcR = HD; srcC = 512; dstR = 512; dstC = NPAD;
        c0 = (bid & 63) * 32; r0 = (bid >> 6) * 32;
    }
    #pragma unroll
    for (int i = 0; i < 32; i += 8) {
        int sr = c0 + ty + i, sc = r0 + tx;
        tile[ty + i][tx] = (sr < srcR && sc < srcC) ? src[(size_t)sr * srcC + sc] : 0.f;
    }
    __syncthreads();
    #pragma unroll
    for (int i = 0; i < 32; i += 8) {
        int dr = r0 + ty + i, dc = c0 + tx;
        if (dr < dstR && dc < dstC)
            dst[(size_t)dr * dstC + dc] = f2bf(tile[tx][ty + i]);
    }
}

// ---- 128x128 BK=64 dbuf counted-vmcnt bf16 GEMM, 16 waves, wave-tile 32x32 ----
// (R27 frozen config: max occupancy + min LDS amplification + XCD swizzle.)
// Wave grid: wr = wid>>2 (0..3, m), wc = wid&3 (0..3, n); acc 2x2.
// LDS 64KB = 2 bufs x [A 16KB | B 16KB], slot-XOR (chunk kq at slot kq^(row&7)).
// Staging: 2 loads/thread/tile -> steady vmcnt(2), never 0 in-loop.
// Bijective XCD-chunked swizzle (m204): same-A-panel n-blocks share an XCD L2.
// MODE 0: out bf16 TRANSPOSED hT[col*MPAD+row], skip cols >= validN (GEMM1)
// MODE 1: out fp32 row-major (ldc=512), skip rows >= validM          (GEMM2)
template<int MODE>
__global__ __launch_bounds__(1024, 8) void gemm_bt(const unsigned short* __restrict__ A,
                        const unsigned short* __restrict__ BT,
                        const float* __restrict__ bias,
                        void* __restrict__ Cout,
                        int K, int lda, int ldc, int validN, int validM) {
    __shared__ unsigned short lds[2][16384];   // 64KB total
    const int t    = threadIdx.x;
    const int wid  = t >> 6, lane = t & 63;
    const int wr   = wid >> 2, wc = wid & 3;
    const int lr   = lane & 15, lh = lane >> 4;

    const int nwg = gridDim.x * gridDim.y;
    const int bid = blockIdx.x + blockIdx.y * gridDim.x;
    const int xcd = bid & 7, idx = bid >> 3;
    const int qc  = nwg >> 3, rc = nwg & 7;
    const int swz = (xcd < rc ? xcd * (qc + 1) : rc * (qc + 1) + (xcd - rc) * qc) + idx;
    const int m0  = (swz / gridDim.x) * 128, n0 = (swz % gridDim.x) * 128;

    const int rr = t >> 3;
    const int qq = (t & 7) ^ (rr & 7);

#define STAGE(buf, kt) do { \
        gload_lds16(A  + (size_t)(m0 + rr) * lda + (kt) + qq * 8, &lds[buf][0]    + t * 8); \
        gload_lds16(BT + (size_t)(n0 + rr) * lda + (kt) + qq * 8, &lds[buf][8192] + t * 8); \
    } while (0)

    f32x4 acc[2][2] = {};
    const int NT = K >> 6;

    STAGE(0, 0);
    for (int tt = 0; tt < NT; ++tt) {
        if (tt + 1 < NT) {
            STAGE((tt + 1) & 1, (tt + 1) * 64);
            asm volatile("s_waitcnt vmcnt(2)" ::: "memory");
        } else {
            asm volatile("s_waitcnt vmcnt(0)" ::: "memory");
        }
        __builtin_amdgcn_s_barrier();
        __builtin_amdgcn_sched_barrier(0);
        const unsigned short* La = &lds[tt & 1][0];
        const unsigned short* Lb = &lds[tt & 1][8192];
        #pragma unroll
        for (int ks = 0; ks < 2; ++ks) {
            const int sl = (ks * 4 + lh) ^ (lr & 7);
            bf16x8 a[2], b[2];
            #pragma unroll
            for (int f = 0; f < 2; ++f) {
                int row = wr * 32 + f * 16 + lr;       // row&7 == lr&7
                a[f] = *(const bf16x8*)(La + row * 64 + sl * 8);
            }
            #pragma unroll
            for (int g = 0; g < 2; ++g) {
                int row = wc * 32 + g * 16 + lr;
                b[g] = *(const bf16x8*)(Lb + row * 64 + sl * 8);
            }
            #pragma unroll
            for (int fm = 0; fm < 2; ++fm)
                #pragma unroll
                for (int fn = 0; fn < 2; ++fn)
                    acc[fm][fn] = __builtin_amdgcn_mfma_f32_16x16x32_bf16(
                        a[fm], b[fn], acc[fm][fn], 0, 0, 0);
        }
        __builtin_amdgcn_s_barrier();
        __builtin_amdgcn_sched_barrier(0);
    }
#undef STAGE

    // C/D layout: col=lane&15, row=(lane>>4)*4+j  [m89 verified]
    if (MODE == 0) {
        unsigned short* smem = &lds[0][0];   // 16384 ushorts = 32KB
        #pragma unroll
        for (int fm = 0; fm < 2; ++fm) {
            #pragma unroll
            for (int fn = 0; fn < 2; ++fn) {
                int lcol = wc * 32 + fn * 16 + lr;
                float bv = bias[n0 + lcol];
                #pragma unroll
                for (int j = 0; j < 4; ++j) {
                    int lrow = wr * 32 + fm * 16 + lh * 4 + j;
                    smem[lcol * 128 + (lrow ^ ((lcol & 15) << 3))] =
                        f2bf(acc[fm][fn][j] + bv);
                }
            }
        }
        __syncthreads();
        unsigned short* hT = (unsigned short*)Cout;
        int col = t >> 3, q = t & 7;     // 8 threads per column, 4 ushort4 each
        int gcol = n0 + col;
        if (gcol < validN) {
            #pragma unroll
            for (int r = 0; r < 4; ++r) {
                int row = q * 16 + r * 4;
                ushort4 v4 = *(const ushort4*)&smem[col * 128 + (row ^ ((col & 15) << 3))];
                *(ushort4*)&hT[(size_t)gcol * MPAD + m0 + row] = v4;
            }
        }
    } else {
        #pragma unroll
        for (int fm = 0; fm < 2; ++fm) {
            #pragma unroll
            for (int fn = 0; fn < 2; ++fn) {
                int gcol = n0 + wc * 32 + fn * 16 + lr;
                float bv = bias[gcol];
                #pragma unroll
                for (int j = 0; j < 4; ++j) {
                    int grow = m0 + wr * 32 + fm * 16 + lh * 4 + j;
                    if (grow < validM)
                        ((float*)Cout)[(size_t)grow * ldc + gcol] = acc[fm][fn][j] + bv;
                }
            }
        }
    }
}

// ---- fold + normalize + relu -> per-(b2,c) padded image (bf16), 8 ch/thread ----
// R28: 2 y-rows per 256-thread block: grid (HP/2, 100); y = 2*bx + (t>>7), x = t&127.
__global__ void fold_norm(const unsigned short* __restrict__ hT, unsigned short* __restrict__ img2) {
    int t  = threadIdx.x;
    int y  = blockIdx.x * 2 + (t >> 7);
    int g  = blockIdx.y;
    int b2 = g / 5, cg = g % 5;
    int c0 = cg * 8;
    int x  = t & 127;
    if (x >= WP) return;
    float val[8] = {};
    if (y >= 3 && y < 63 && x >= 3 && x < 111) {
        int kiA[3], biA[3], nki = 0;
        for (int ki = y % 3; ki < 7; ki += 3) {
            int bi = (y - ki) / 3;
            if (y - ki >= 0 && bi < 20) { kiA[nki] = ki; biA[nki] = bi; ++nki; }
        }
        int kjA[3], bjA[3], nkj = 0;
        for (int kj = x % 3; kj < 7; kj += 3) {
            int bj = (x - kj) / 3;
            if (x - kj >= 0 && bj < 36) { kjA[nkj] = kj; bjA[nkj] = bj; ++nkj; }
        }
        float s[8] = {};
        for (int i = 0; i < nki; ++i) {
            for (int j = 0; j < nkj; ++j) {
                int row = b2 * NVECS + biA[i] * 36 + bjA[j];
                int colb = kiA[i] * 7 + kjA[j];
                #pragma unroll
                for (int q = 0; q < 8; ++q)
                    s[q] += bf2f(hT[(size_t)((c0 + q) * 49 + colb) * MPAD + row]);
            }
        }
        float inv = 1.f / (float)(nki * nkj);
        #pragma unroll
        for (int q = 0; q < 8; ++q)
            val[q] = fmaxf(s[q] * inv, 0.f);
    }
    #pragma unroll
    for (int q = 0; q < 8; ++q)
        img2[(size_t)(b2 * 40 + c0 + q) * IMGPIX + y * WP + x] = f2bf(val[q]);
}

// ---- unfold, LDS-staged (R28: 512 threads) ----
__global__ void unfold_k(const unsigned short* __restrict__ img2, unsigned short* __restrict__ h2b) {
    __shared__ unsigned short lds[20 * 798];
    __shared__ unsigned short lut[980];
    const int gb = blockIdx.x;                 // b2*20 + bi
    const int cg = blockIdx.y;
    const int b2 = gb / 20, bi = gb % 20;
    const int t  = threadIdx.x;

    const unsigned short* src = img2 + (size_t)(b2 * 40 + cg * 20) * IMGPIX + (bi * 3) * WP;
    for (int p = t; p < 7980; p += 512) {
        int cc = p / 399, rem2 = p - cc * 399;
        *(ushort2*)&lds[cc * 798 + rem2 * 2] =
            *(const ushort2*)&src[(size_t)cc * IMGPIX + rem2 * 2];
    }
    for (int L = t; L < 980; L += 512) {
        int cc = L / 49, kk = L - cc * 49;
        lut[L] = (unsigned short)(cc * 798 + (kk / 7) * 114 + (kk % 7));
    }
    __syncthreads();

    const int cpr   = (cg == 0) ? 245 : 267;
    const int total = 36 * cpr;
    const int rowbase = b2 * NVECS + bi * 36;
    const int hdbase  = cg * 980;
    for (int i = t; i < total; i += 512) {
        int r = i / cpr, q = i - r * cpr;
        int hl = q * 4;
        ushort4 v;
        unsigned short* vv = (unsigned short*)&v;
        #pragma unroll
        for (int e = 0; e < 4; ++e) {
            int h = hl + e;
            vv[e] = (h < 980) ? lds[lut[h] + r * 3] : (unsigned short)0;
        }
        *(ushort4*)&h2b[(size_t)(rowbase + r) * NPAD + hdbase + hl] = v;
    }
}

extern "C" void kernel_launch(void* const* d_in, const int* in_sizes, int n_in,
                              void* d_out, int out_size, void* d_ws, size_t ws_size,
                              hipStream_t stream) {
    const float* x  = (const float*)d_in[0];
    const float* W1 = (const float*)d_in[1];
    const float* b1 = (const float*)d_in[2];
    const float* W2 = (const float*)d_in[3];
    const float* b2 = (const float*)d_in[4];
    float* out = (float*)d_out;

    unsigned short* xb   = (unsigned short*)d_ws;                 // MPAD*512
    unsigned short* W1T  = xb   + (size_t)MPAD * D_MODEL;         // 2048*512
    unsigned short* W2T  = W1T  + (size_t)NPAD * D_MODEL;         // 512*2048
    unsigned short* hT   = W2T  + (size_t)D_MODEL * NPAD;         // NPAD*MPAD (transposed)
    unsigned short* h2b  = hT   + (size_t)NPAD * MPAD;            // MPAD*NPAD
    unsigned short* img2 = h2b  + (size_t)MPAD * NPAD;            // 800*7524

    prep<<<dim3((MPAD * D_MODEL / 4 + 255) / 256, 1, 3), 256, 0, stream>>>(
        x, xb, W1, W1T, W2, W2T);

    // GEMM1: hT = (xb @ W1T^T + b1)^T   (bf16, transposed out), grid 16x113, 1024 thr
    gemm_bt<0><<<dim3(NPAD / 128, MPAD / 128), 1024, 0, stream>>>(
        xb, W1T, b1, hT, D_MODEL, D_MODEL, 0, HD, MPAD);

    fold_norm<<<dim3(HP / 2, 100), 256, 0, stream>>>(hT, img2);
    unfold_k<<<dim3(400, 2), 512, 0, stream>>>(img2, h2b);

    // GEMM2: out = h2b @ W2T^T + b2  (fp32, rows<14400), grid 4x113, 1024 thr, K=1984
    gemm_bt<1><<<dim3(512 / 128, MPAD / 128), 1024, 0, stream>>>(
        h2b, W2T, b2, out, KEFF2, NPAD, D_MODEL, D_MODEL, MROWS);
}